// Round 2
// baseline (898.326 us; speedup 1.0000x reference)
//
#include <hip/hip_runtime.h>
#include <hip/hip_cooperative_groups.h>
#include <math.h>

#define NSB   512   // edge-chunk blocks for bucket pass
#define BSH   8     // 256 nodes per bucket
#define BKN   256   // nodes per bucket
#define ESMAX 6272  // max edges per chunk (ceil(3.2M/512)=6250)
#define SLOT  10240 // col/col2 region size per bucket (avg fill 8192, +23 sigma)

typedef _Float16 h8  __attribute__((ext_vector_type(8)));
typedef _Float16 h4  __attribute__((ext_vector_type(4)));
typedef _Float16 h2v __attribute__((ext_vector_type(2)));

// Shared-memory overlay for the phases (max member = sort: 43 KB)
union SU {
    struct {
        unsigned sorted[ESMAX];
        int lc[512], lofE[512], lcur[512], soff[512];
        int wsum[8];
        unsigned char sbuck[ESMAX];
    } b;                                    // bucket phase: 39.6 KB
    struct {
        int sdat[SLOT];
        int cnt[BKN], cur[BKN];
        int wsum[4];
    } s;                                    // sort phase: 43.0 KB
    struct { float sW[2048]; } l;           // linear1: 8 KB
    struct { float sW[256]; float sb[16]; } p; // pull epilogues: 1.1 KB
};

// 64-lane inclusive scan (no barriers)
__device__ inline int wave_scan_incl(int v) {
    int lane = threadIdx.x & 63;
#pragma unroll
    for (int d = 1; d < 64; d <<= 1) {
        int t = __shfl_up(v, d, 64);
        if (lane >= d) v += t;
    }
    return v;
}

__device__ inline void gsync(cooperative_groups::grid_group& g) {
    __threadfence();   // release: writeback L2 (cross-XCD)
    g.sync();
    __threadfence();   // acquire: invalidate stale L1/L2
}

// ================= one cooperative kernel, 7 phases =================

__global__ __launch_bounds__(512, 4) void k_mega(
        const float* __restrict__ x, const int* __restrict__ srcv, const int* __restrict__ dstv,
        const float* __restrict__ W1, const float* __restrict__ bias1,
        const float* __restrict__ W2, const float* __restrict__ bias2,
        const float* __restrict__ W3, const float* __restrict__ bias3,
        int* __restrict__ gcur, unsigned* __restrict__ col, int* __restrict__ col2,
        int* __restrict__ rs, int* __restrict__ re, float* __restrict__ dis,
        _Float16* __restrict__ hsA, _Float16* __restrict__ hsB, _Float16* __restrict__ hs2,
        float* __restrict__ out, int n, int e, int nbuck, int es)
{
    cooperative_groups::grid_group grid = cooperative_groups::this_grid();
    __shared__ SU su;
    int tid = threadIdx.x;

    // ---------- P0: zero bucket cursors ----------
    for (int i = blockIdx.x * 512 + tid; i < nbuck; i += gridDim.x * 512)
        gcur[i] = 0;
    gsync(grid);

    // ---------- P1: bucket pass (LDS counting sort + atomic region alloc) ----------
    for (int blk = blockIdx.x; blk * es < e; blk += gridDim.x) {
        su.b.lc[tid] = 0;
        __syncthreads();
        int lo = blk * es;
        int hi = min(lo + es, e);
        for (int i = lo + tid; i < hi; i += 512)
            atomicAdd(&su.b.lc[dstv[i] >> BSH], 1);
        __syncthreads();
        int c = su.b.lc[tid];
        int inc = wave_scan_incl(c);
        int wid = tid >> 6;
        if ((tid & 63) == 63) su.b.wsum[wid] = inc;
        __syncthreads();
        int wofs = 0;
#pragma unroll
        for (int w = 0; w < 8; w++) wofs += (w < wid) ? su.b.wsum[w] : 0;
        int excl = inc - c + wofs;
        su.b.lofE[tid] = excl;
        su.b.lcur[tid] = excl;
        if (tid < nbuck && c > 0)
            su.b.soff[tid] = tid * SLOT + atomicAdd(&gcur[tid], c);
        __syncthreads();
        for (int i = lo + tid; i < hi; i += 512) {
            int d = dstv[i];
            int bb = d >> BSH;
            int p = atomicAdd(&su.b.lcur[bb], 1);
            su.b.sorted[p] = ((unsigned)srcv[i] << BSH) | (unsigned)(d & (BKN - 1));
            su.b.sbuck[p] = (unsigned char)(bb & 255);
        }
        __syncthreads();
        int cnt_ = hi - lo;
        int split = (nbuck > 256) ? su.b.lofE[256] : 0x7fffffff;
        for (int i = tid; i < cnt_; i += 512) {
            int bb = su.b.sbuck[i] | ((i >= split) ? 256 : 0);
            col[su.b.soff[bb] + (i - su.b.lofE[bb])] = su.b.sorted[i];
        }
        __syncthreads();
    }
    gsync(grid);

    // ---------- P2: per-bucket counting sort -> CSR + dis ----------
    for (int bk = blockIdx.x; bk < nbuck; bk += gridDim.x) {
        int lo = bk * SLOT;
        int tot = gcur[bk];
        int hi = lo + tot;
        if (tid < BKN) su.s.cnt[tid] = 0;
        __syncthreads();
        for (int i = lo + tid; i < hi; i += 512)
            atomicAdd(&su.s.cnt[col[i] & (BKN - 1u)], 1);
        __syncthreads();
        int c = (tid < BKN) ? su.s.cnt[tid] : 0;
        int inc = wave_scan_incl(c);
        int wid = tid >> 6;
        if (tid < BKN && (tid & 63) == 63) su.s.wsum[wid] = inc;
        __syncthreads();
        if (tid < BKN) {
            int wofs = 0;
#pragma unroll
            for (int w = 0; w < 4; w++) wofs += (w < wid) ? su.s.wsum[w] : 0;
            int excl = inc - c + wofs;
            su.s.cur[tid] = excl;
            int node = (bk << BSH) + tid;
            if (node < n) {
                rs[node] = lo + excl;
                re[node] = lo + excl + c;
                dis[node] = rsqrtf((float)(c + 1));
            }
        }
        __syncthreads();
        for (int i = lo + tid; i < hi; i += 512) {
            unsigned v = col[i];
            int pos = atomicAdd(&su.s.cur[v & (BKN - 1u)], 1);
            su.s.sdat[pos] = (int)(v >> BSH);
        }
        __syncthreads();
        for (int i = tid; i < tot; i += 512)
            col2[lo + i] = su.s.sdat[i];
        __syncthreads();
    }
    gsync(grid);

    // ---------- P3: layer-1 linear  hsA = (x @ W1) * dis ----------
    {
        for (int i = tid; i < 2048; i += 512) su.l.sW[i] = W1[i];
        __syncthreads();
        int cgi = tid & 3;
        int kg = (tid >> 2) & 7;
        int nl = tid >> 5;
        float wr[16][4];
#pragma unroll
        for (int j = 0; j < 16; j++)
#pragma unroll
            for (int cc = 0; cc < 4; cc++)
                wr[j][cc] = su.l.sW[(kg * 16 + j) * 16 + cgi * 4 + cc];
        for (int base = blockIdx.x * 128; base < n; base += gridDim.x * 128) {
            int nodeBase = base + nl;
            for (int it = 0; it < 8; it++) {
                int node = nodeBase + it * 16;
                float a0 = 0.f, a1 = 0.f, a2 = 0.f, a3 = 0.f;
                if (node < n) {
                    const float4* xr = (const float4*)(x + (size_t)node * 128 + kg * 16);
#pragma unroll
                    for (int j4 = 0; j4 < 4; j4++) {
                        float4 xv = xr[j4];
                        float xs0 = xv.x, xs1 = xv.y, xs2 = xv.z, xs3 = xv.w;
                        int j = j4 * 4;
                        a0 += xs0 * wr[j][0] + xs1 * wr[j+1][0] + xs2 * wr[j+2][0] + xs3 * wr[j+3][0];
                        a1 += xs0 * wr[j][1] + xs1 * wr[j+1][1] + xs2 * wr[j+2][1] + xs3 * wr[j+3][1];
                        a2 += xs0 * wr[j][2] + xs1 * wr[j+1][2] + xs2 * wr[j+2][2] + xs3 * wr[j+3][2];
                        a3 += xs0 * wr[j][3] + xs1 * wr[j+1][3] + xs2 * wr[j+2][3] + xs3 * wr[j+3][3];
                    }
                }
#pragma unroll
                for (int m = 4; m <= 16; m <<= 1) {
                    a0 += __shfl_xor(a0, m);
                    a1 += __shfl_xor(a1, m);
                    a2 += __shfl_xor(a2, m);
                    a3 += __shfl_xor(a3, m);
                }
                if (kg == 0 && node < n) {
                    float d = dis[node];
                    h4 o;
                    o[0] = (_Float16)(a0 * d);
                    o[1] = (_Float16)(a1 * d);
                    o[2] = (_Float16)(a2 * d);
                    o[3] = (_Float16)(a3 * d);
                    *((h4*)(hsA + (size_t)node * 16 + cgi * 4)) = o;
                }
            }
        }
    }
    gsync(grid);

    // ---------- P4: agg1 + 16x16 linear (4 lanes/node) ----------
    {
        if (tid < 256) su.p.sW[tid] = W2[tid];
        if (tid < 16)  su.p.sb[tid] = bias1[tid];
        __syncthreads();
        const h8* H = (const h8*)hsA;
        long long stride = (long long)gridDim.x * 512;
        for (long long t = (long long)blockIdx.x * 512 + tid; (t >> 2) < (long long)n; t += stride) {
            int node = (int)(t >> 2), qt = (int)(t & 3);
            float acc[16];
            if (qt == 0) {
                h8 s0 = H[(size_t)node * 2];
                h8 s1 = H[(size_t)node * 2 + 1];
#pragma unroll
                for (int j = 0; j < 8; j++) { acc[j] = (float)s0[j]; acc[8 + j] = (float)s1[j]; }
            } else {
#pragma unroll
                for (int j = 0; j < 16; j++) acc[j] = 0.f;
            }
            int b0i = rs[node], e2 = re[node];
            int i = b0i + qt;
            for (; i + 12 < e2; i += 16) {
                int s0 = col2[i], s1 = col2[i + 4], s2 = col2[i + 8], s3 = col2[i + 12];
                h8 y0 = H[(size_t)s0 * 2], z0 = H[(size_t)s0 * 2 + 1];
                h8 y1 = H[(size_t)s1 * 2], z1 = H[(size_t)s1 * 2 + 1];
                h8 y2 = H[(size_t)s2 * 2], z2 = H[(size_t)s2 * 2 + 1];
                h8 y3 = H[(size_t)s3 * 2], z3 = H[(size_t)s3 * 2 + 1];
#pragma unroll
                for (int j = 0; j < 8; j++) {
                    acc[j]     += (float)y0[j] + (float)y1[j] + (float)y2[j] + (float)y3[j];
                    acc[8 + j] += (float)z0[j] + (float)z1[j] + (float)z2[j] + (float)z3[j];
                }
            }
            for (; i < e2; i += 4) {
                int s = col2[i];
                h8 y = H[(size_t)s * 2], z = H[(size_t)s * 2 + 1];
#pragma unroll
                for (int j = 0; j < 8; j++) { acc[j] += (float)y[j]; acc[8 + j] += (float)z[j]; }
            }
#pragma unroll
            for (int j = 0; j < 16; j++) {
                acc[j] += __shfl_xor(acc[j], 1);
                acc[j] += __shfl_xor(acc[j], 2);
            }
            float d = dis[node];
            float va[16];
#pragma unroll
            for (int k = 0; k < 16; k++) {
                float v = acc[k] * d + su.p.sb[k];
                va[k] = v > 0.f ? v : 0.f;
            }
            h4 o;
#pragma unroll
            for (int cc = 0; cc < 4; cc++) {
                int cidx = (qt << 2) + cc;
                float s = 0.f;
#pragma unroll
                for (int k = 0; k < 16; k++) s += va[k] * su.p.sW[k * 16 + cidx];
                o[cc] = (_Float16)(s * d);
            }
            *((h4*)(hsB + (size_t)node * 16 + (qt << 2))) = o;
        }
    }
    gsync(grid);

    // ---------- P5: agg2 + 16x2 linear (4 lanes/node) ----------
    {
        if (tid < 32) su.p.sW[tid] = W3[tid];
        if (tid < 16) su.p.sb[tid] = bias2[tid];
        __syncthreads();
        const h8* H = (const h8*)hsB;
        long long stride = (long long)gridDim.x * 512;
        for (long long t = (long long)blockIdx.x * 512 + tid; (t >> 2) < (long long)n; t += stride) {
            int node = (int)(t >> 2), qt = (int)(t & 3);
            float acc[16];
            if (qt == 0) {
                h8 s0 = H[(size_t)node * 2];
                h8 s1 = H[(size_t)node * 2 + 1];
#pragma unroll
                for (int j = 0; j < 8; j++) { acc[j] = (float)s0[j]; acc[8 + j] = (float)s1[j]; }
            } else {
#pragma unroll
                for (int j = 0; j < 16; j++) acc[j] = 0.f;
            }
            int b0i = rs[node], e2 = re[node];
            int i = b0i + qt;
            for (; i + 12 < e2; i += 16) {
                int s0 = col2[i], s1 = col2[i + 4], s2 = col2[i + 8], s3 = col2[i + 12];
                h8 y0 = H[(size_t)s0 * 2], z0 = H[(size_t)s0 * 2 + 1];
                h8 y1 = H[(size_t)s1 * 2], z1 = H[(size_t)s1 * 2 + 1];
                h8 y2 = H[(size_t)s2 * 2], z2 = H[(size_t)s2 * 2 + 1];
                h8 y3 = H[(size_t)s3 * 2], z3 = H[(size_t)s3 * 2 + 1];
#pragma unroll
                for (int j = 0; j < 8; j++) {
                    acc[j]     += (float)y0[j] + (float)y1[j] + (float)y2[j] + (float)y3[j];
                    acc[8 + j] += (float)z0[j] + (float)z1[j] + (float)z2[j] + (float)z3[j];
                }
            }
            for (; i < e2; i += 4) {
                int s = col2[i];
                h8 y = H[(size_t)s * 2], z = H[(size_t)s * 2 + 1];
#pragma unroll
                for (int j = 0; j < 8; j++) { acc[j] += (float)y[j]; acc[8 + j] += (float)z[j]; }
            }
#pragma unroll
            for (int j = 0; j < 16; j++) {
                acc[j] += __shfl_xor(acc[j], 1);
                acc[j] += __shfl_xor(acc[j], 2);
            }
            float d = dis[node];
            float p0 = 0.f, p1 = 0.f;
#pragma unroll
            for (int k = 0; k < 16; k++) {
                float v = acc[k] * d + su.p.sb[k];
                v = v > 0.f ? v : 0.f;
                p0 += v * su.p.sW[k * 2 + 0];
                p1 += v * su.p.sW[k * 2 + 1];
            }
            if (qt == 0) {
                h2v o;
                o[0] = (_Float16)(p0 * d);
                o[1] = (_Float16)(p1 * d);
                ((h2v*)hs2)[node] = o;
            }
        }
    }
    gsync(grid);

    // ---------- P6: agg3 + bias + log_softmax (4 lanes/node) ----------
    {
        const h2v* H = (const h2v*)hs2;
        float bz0 = bias3[0], bz1 = bias3[1];
        long long stride = (long long)gridDim.x * 512;
        for (long long t = (long long)blockIdx.x * 512 + tid; (t >> 2) < (long long)n; t += stride) {
            int node = (int)(t >> 2), qt = (int)(t & 3);
            float a0 = 0.f, a1 = 0.f;
            if (qt == 0) {
                h2v self = H[node];
                a0 = (float)self[0]; a1 = (float)self[1];
            }
            int b0i = rs[node], e2 = re[node];
            int i = b0i + qt;
            for (; i + 12 < e2; i += 16) {
                h2v v0 = H[col2[i]];
                h2v v1 = H[col2[i + 4]];
                h2v v2 = H[col2[i + 8]];
                h2v v3 = H[col2[i + 12]];
                a0 += (float)v0[0] + (float)v1[0] + (float)v2[0] + (float)v3[0];
                a1 += (float)v0[1] + (float)v1[1] + (float)v2[1] + (float)v3[1];
            }
            for (; i < e2; i += 4) {
                h2v v = H[col2[i]];
                a0 += (float)v[0];
                a1 += (float)v[1];
            }
            a0 += __shfl_xor(a0, 1); a0 += __shfl_xor(a0, 2);
            a1 += __shfl_xor(a1, 1); a1 += __shfl_xor(a1, 2);
            if (qt == 0) {
                float d = dis[node];
                float z0 = a0 * d + bz0;
                float z1 = a1 * d + bz1;
                float m = fmaxf(z0, z1);
                float l = m + logf(expf(z0 - m) + expf(z1 - m));
                float2 o = {z0 - l, z1 - l};
                ((float2*)out)[node] = o;
            }
        }
    }
}

// ================= launch =================

extern "C" void kernel_launch(void* const* d_in, const int* in_sizes, int n_in,
                              void* d_out, int out_size, void* d_ws, size_t ws_size,
                              hipStream_t stream) {
    const float* x  = (const float*)d_in[0];
    const int*   ei = (const int*)d_in[1];
    const float* W1 = (const float*)d_in[2];
    const float* b1 = (const float*)d_in[3];
    const float* W2 = (const float*)d_in[4];
    const float* b2 = (const float*)d_in[5];
    const float* W3 = (const float*)d_in[6];
    const float* b3 = (const float*)d_in[7];
    float* out = (float*)d_out;

    int N = in_sizes[0] / 128;
    int E = in_sizes[1] / 2;
    const int* src = ei;
    const int* dst = ei + E;

    int NBUCK = (N + BKN - 1) >> BSH;            // 391 for N=100000 (<= 512)
    int ES = (E + NSB - 1) / NSB;                // 6250 (<= ESMAX)

    char* ws = (char*)d_ws;
    size_t off = 0;
    auto alloc = [&](size_t bytes) {
        void* p = ws + off;
        off += (bytes + 255) & ~(size_t)255;
        return p;
    };
    int*       gcur = (int*)alloc((size_t)NBUCK * sizeof(int));
    unsigned*  col  = (unsigned*)alloc((size_t)NBUCK * SLOT * sizeof(unsigned));
    int*       col2 = (int*)alloc((size_t)NBUCK * SLOT * sizeof(int));
    int*       rs   = (int*)alloc((size_t)N * sizeof(int));
    int*       re   = (int*)alloc((size_t)N * sizeof(int));
    float*     dis  = (float*)alloc((size_t)N * sizeof(float));
    _Float16*  hsA  = (_Float16*)alloc((size_t)N * 16 * sizeof(_Float16));
    _Float16*  hsB  = (_Float16*)alloc((size_t)N * 16 * sizeof(_Float16));
    _Float16*  hs2  = (_Float16*)alloc((size_t)N * 2 * sizeof(_Float16));

    // Co-resident grid size (cached): blocks/CU from occupancy API x CU count.
    static int gridBlocks = 0;
    if (gridBlocks == 0) {
        int mb = 0;
        if (hipOccupancyMaxActiveBlocksPerMultiprocessor(&mb, k_mega, 512, 0) != hipSuccess || mb < 1)
            mb = 2;   // known-safe: 43KB LDS, <=128 VGPR (launch_bounds) -> 2 blocks/CU
        int ncu = 256;
        int dev = 0;
        hipGetDevice(&dev);
        hipDeviceGetAttribute(&ncu, hipDeviceAttributeMultiprocessorCount, dev);
        long long g = (long long)mb * ncu;
        if (g > 1024) g = 1024;
        gridBlocks = (int)g;
    }

    void* args[] = { &x, &src, &dst, &W1, &b1, &W2, &b2, &W3, &b3,
                     &gcur, &col, &col2, &rs, &re, &dis, &hsA, &hsB, &hs2,
                     &out, &N, &E, &NBUCK, &ES };
    hipLaunchCooperativeKernel((void*)k_mega, dim3(gridBlocks), dim3(512),
                               args, 0, stream);
}

// Round 3
// 823.294 us; speedup vs baseline: 1.0911x; 1.0911x over previous
//
#include <hip/hip_runtime.h>
#include <hip/hip_cooperative_groups.h>
#include <math.h>

#define NSB   512   // edge-chunk blocks for bucket pass
#define BSH   8     // 256 nodes per bucket
#define BKN   256   // nodes per bucket
#define ESMAX 6272  // max edges per chunk (ceil(3.2M/512)=6250)
#define SLOT  10240 // col/col2 region size per bucket (avg fill 8192, +23 sigma)

typedef _Float16 h8  __attribute__((ext_vector_type(8)));
typedef _Float16 h4  __attribute__((ext_vector_type(4)));
typedef _Float16 h2v __attribute__((ext_vector_type(2)));

// Shared-memory overlay for the phases (max member = sort: 43 KB)
union SU {
    struct {
        unsigned sorted[ESMAX];
        int lc[512], lofE[512], lcur[512], soff[512];
        int wsum[8];
        unsigned char sbuck[ESMAX];
    } b;                                    // bucket phase: 39.6 KB
    struct {
        int sdat[SLOT];
        int cnt[BKN], cur[BKN];
        int wsum[4];
    } s;                                    // sort phase: 43.0 KB
    struct { float sW[2048]; } l;           // linear1: 8 KB
    struct { float sW[256]; float sb[16]; } p; // pull epilogues: 1.1 KB
};

// 64-lane inclusive scan (no barriers)
__device__ inline int wave_scan_incl(int v) {
    int lane = threadIdx.x & 63;
#pragma unroll
    for (int d = 1; d < 64; d <<= 1) {
        int t = __shfl_up(v, d, 64);
        if (lane >= d) v += t;
    }
    return v;
}

__device__ inline void gsync(cooperative_groups::grid_group& g) {
    __threadfence();   // release: writeback (cross-XCD)
    g.sync();
    __threadfence();   // acquire
}

// ================= one cooperative kernel, 6 phases =================
// amdgpu_waves_per_eu(4,4): pin occupancy target to exactly 4 waves/EU
// -> VGPR budget 128, no spills (round-2 lesson: launch_bounds(512,4) let the
//    occupancy heuristic boost to 8 waves/EU = 64 VGPR and spill every phase).

__global__ __attribute__((amdgpu_flat_work_group_size(512, 512), amdgpu_waves_per_eu(4, 4)))
void k_mega(
        const float* __restrict__ x, const int* __restrict__ srcv, const int* __restrict__ dstv,
        const float* __restrict__ W1, const float* __restrict__ bias1,
        const float* __restrict__ W2, const float* __restrict__ bias2,
        const float* __restrict__ W3, const float* __restrict__ bias3,
        int* __restrict__ gcur, unsigned* __restrict__ col, int* __restrict__ col2,
        int* __restrict__ rs, int* __restrict__ re, float* __restrict__ dis,
        _Float16* __restrict__ hsA, _Float16* __restrict__ hsB, _Float16* __restrict__ hs2,
        float* __restrict__ out, int n, int e, int nbuck, int es)
{
    cooperative_groups::grid_group grid = cooperative_groups::this_grid();
    __shared__ SU su;
    int tid = threadIdx.x;

    // ---------- P1: bucket pass (LDS counting sort + atomic region alloc) ----------
    // gcur zeroed by host-side hipMemsetAsync before launch.
    for (int blk = blockIdx.x; blk * es < e; blk += gridDim.x) {
        su.b.lc[tid] = 0;
        __syncthreads();
        int lo = blk * es;
        int hi = min(lo + es, e);
        for (int i = lo + tid; i < hi; i += 512)
            atomicAdd(&su.b.lc[dstv[i] >> BSH], 1);
        __syncthreads();
        int c = su.b.lc[tid];
        int inc = wave_scan_incl(c);
        int wid = tid >> 6;
        if ((tid & 63) == 63) su.b.wsum[wid] = inc;
        __syncthreads();
        int wofs = 0;
#pragma unroll
        for (int w = 0; w < 8; w++) wofs += (w < wid) ? su.b.wsum[w] : 0;
        int excl = inc - c + wofs;
        su.b.lofE[tid] = excl;
        su.b.lcur[tid] = excl;
        if (tid < nbuck && c > 0)
            su.b.soff[tid] = tid * SLOT + atomicAdd(&gcur[tid], c);
        __syncthreads();
        for (int i = lo + tid; i < hi; i += 512) {
            int d = dstv[i];
            int bb = d >> BSH;
            int p = atomicAdd(&su.b.lcur[bb], 1);
            su.b.sorted[p] = ((unsigned)srcv[i] << BSH) | (unsigned)(d & (BKN - 1));
            su.b.sbuck[p] = (unsigned char)(bb & 255);
        }
        __syncthreads();
        int cnt_ = hi - lo;
        int split = (nbuck > 256) ? su.b.lofE[256] : 0x7fffffff;
        for (int i = tid; i < cnt_; i += 512) {
            int bb = su.b.sbuck[i] | ((i >= split) ? 256 : 0);
            col[su.b.soff[bb] + (i - su.b.lofE[bb])] = su.b.sorted[i];
        }
        __syncthreads();
    }
    gsync(grid);

    // ---------- P2: per-bucket counting sort -> CSR + dis ----------
    for (int bk = blockIdx.x; bk < nbuck; bk += gridDim.x) {
        int lo = bk * SLOT;
        int tot = gcur[bk];
        int hi = lo + tot;
        if (tid < BKN) su.s.cnt[tid] = 0;
        __syncthreads();
        for (int i = lo + tid; i < hi; i += 512)
            atomicAdd(&su.s.cnt[col[i] & (BKN - 1u)], 1);
        __syncthreads();
        int c = (tid < BKN) ? su.s.cnt[tid] : 0;
        int inc = wave_scan_incl(c);
        int wid = tid >> 6;
        if (tid < BKN && (tid & 63) == 63) su.s.wsum[wid] = inc;
        __syncthreads();
        if (tid < BKN) {
            int wofs = 0;
#pragma unroll
            for (int w = 0; w < 4; w++) wofs += (w < wid) ? su.s.wsum[w] : 0;
            int excl = inc - c + wofs;
            su.s.cur[tid] = excl;
            int node = (bk << BSH) + tid;
            if (node < n) {
                rs[node] = lo + excl;
                re[node] = lo + excl + c;
                dis[node] = rsqrtf((float)(c + 1));
            }
        }
        __syncthreads();
        for (int i = lo + tid; i < hi; i += 512) {
            unsigned v = col[i];
            int pos = atomicAdd(&su.s.cur[v & (BKN - 1u)], 1);
            su.s.sdat[pos] = (int)(v >> BSH);
        }
        __syncthreads();
        for (int i = tid; i < tot; i += 512)
            col2[lo + i] = su.s.sdat[i];
        __syncthreads();
    }
    gsync(grid);

    // ---------- P3: layer-1 linear  hsA = (x @ W1) * dis ----------
    {
        for (int i = tid; i < 2048; i += 512) su.l.sW[i] = W1[i];
        __syncthreads();
        int cgi = tid & 3;
        int kg = (tid >> 2) & 7;
        int nl = tid >> 5;
        float wr[16][4];
#pragma unroll
        for (int j = 0; j < 16; j++)
#pragma unroll
            for (int cc = 0; cc < 4; cc++)
                wr[j][cc] = su.l.sW[(kg * 16 + j) * 16 + cgi * 4 + cc];
        for (int base = blockIdx.x * 128; base < n; base += gridDim.x * 128) {
            int nodeBase = base + nl;
            for (int it = 0; it < 8; it++) {
                int node = nodeBase + it * 16;
                float a0 = 0.f, a1 = 0.f, a2 = 0.f, a3 = 0.f;
                if (node < n) {
                    const float4* xr = (const float4*)(x + (size_t)node * 128 + kg * 16);
#pragma unroll
                    for (int j4 = 0; j4 < 4; j4++) {
                        float4 xv = xr[j4];
                        float xs0 = xv.x, xs1 = xv.y, xs2 = xv.z, xs3 = xv.w;
                        int j = j4 * 4;
                        a0 += xs0 * wr[j][0] + xs1 * wr[j+1][0] + xs2 * wr[j+2][0] + xs3 * wr[j+3][0];
                        a1 += xs0 * wr[j][1] + xs1 * wr[j+1][1] + xs2 * wr[j+2][1] + xs3 * wr[j+3][1];
                        a2 += xs0 * wr[j][2] + xs1 * wr[j+1][2] + xs2 * wr[j+2][2] + xs3 * wr[j+3][2];
                        a3 += xs0 * wr[j][3] + xs1 * wr[j+1][3] + xs2 * wr[j+2][3] + xs3 * wr[j+3][3];
                    }
                }
#pragma unroll
                for (int m = 4; m <= 16; m <<= 1) {
                    a0 += __shfl_xor(a0, m);
                    a1 += __shfl_xor(a1, m);
                    a2 += __shfl_xor(a2, m);
                    a3 += __shfl_xor(a3, m);
                }
                if (kg == 0 && node < n) {
                    float d = dis[node];
                    h4 o;
                    o[0] = (_Float16)(a0 * d);
                    o[1] = (_Float16)(a1 * d);
                    o[2] = (_Float16)(a2 * d);
                    o[3] = (_Float16)(a3 * d);
                    *((h4*)(hsA + (size_t)node * 16 + cgi * 4)) = o;
                }
            }
        }
    }
    gsync(grid);

    // ---------- P4: agg1 + 16x16 linear (4 lanes/node) ----------
    {
        if (tid < 256) su.p.sW[tid] = W2[tid];
        if (tid < 16)  su.p.sb[tid] = bias1[tid];
        __syncthreads();
        const h8* H = (const h8*)hsA;
        long long stride = (long long)gridDim.x * 512;
        for (long long t = (long long)blockIdx.x * 512 + tid; (t >> 2) < (long long)n; t += stride) {
            int node = (int)(t >> 2), qt = (int)(t & 3);
            float acc[16];
            if (qt == 0) {
                h8 s0 = H[(size_t)node * 2];
                h8 s1 = H[(size_t)node * 2 + 1];
#pragma unroll
                for (int j = 0; j < 8; j++) { acc[j] = (float)s0[j]; acc[8 + j] = (float)s1[j]; }
            } else {
#pragma unroll
                for (int j = 0; j < 16; j++) acc[j] = 0.f;
            }
            int b0i = rs[node], e2 = re[node];
            int i = b0i + qt;
            for (; i + 12 < e2; i += 16) {
                int s0 = col2[i], s1 = col2[i + 4], s2 = col2[i + 8], s3 = col2[i + 12];
                h8 y0 = H[(size_t)s0 * 2], z0 = H[(size_t)s0 * 2 + 1];
                h8 y1 = H[(size_t)s1 * 2], z1 = H[(size_t)s1 * 2 + 1];
                h8 y2 = H[(size_t)s2 * 2], z2 = H[(size_t)s2 * 2 + 1];
                h8 y3 = H[(size_t)s3 * 2], z3 = H[(size_t)s3 * 2 + 1];
#pragma unroll
                for (int j = 0; j < 8; j++) {
                    acc[j]     += (float)y0[j] + (float)y1[j] + (float)y2[j] + (float)y3[j];
                    acc[8 + j] += (float)z0[j] + (float)z1[j] + (float)z2[j] + (float)z3[j];
                }
            }
            for (; i < e2; i += 4) {
                int s = col2[i];
                h8 y = H[(size_t)s * 2], z = H[(size_t)s * 2 + 1];
#pragma unroll
                for (int j = 0; j < 8; j++) { acc[j] += (float)y[j]; acc[8 + j] += (float)z[j]; }
            }
#pragma unroll
            for (int j = 0; j < 16; j++) {
                acc[j] += __shfl_xor(acc[j], 1);
                acc[j] += __shfl_xor(acc[j], 2);
            }
            float d = dis[node];
            float va[16];
#pragma unroll
            for (int k = 0; k < 16; k++) {
                float v = acc[k] * d + su.p.sb[k];
                va[k] = v > 0.f ? v : 0.f;
            }
            h4 o;
#pragma unroll
            for (int cc = 0; cc < 4; cc++) {
                int cidx = (qt << 2) + cc;
                float s = 0.f;
#pragma unroll
                for (int k = 0; k < 16; k++) s += va[k] * su.p.sW[k * 16 + cidx];
                o[cc] = (_Float16)(s * d);
            }
            *((h4*)(hsB + (size_t)node * 16 + (qt << 2))) = o;
        }
    }
    gsync(grid);

    // ---------- P5: agg2 + 16x2 linear (4 lanes/node) ----------
    {
        if (tid < 32) su.p.sW[tid] = W3[tid];
        if (tid < 16) su.p.sb[tid] = bias2[tid];
        __syncthreads();
        const h8* H = (const h8*)hsB;
        long long stride = (long long)gridDim.x * 512;
        for (long long t = (long long)blockIdx.x * 512 + tid; (t >> 2) < (long long)n; t += stride) {
            int node = (int)(t >> 2), qt = (int)(t & 3);
            float acc[16];
            if (qt == 0) {
                h8 s0 = H[(size_t)node * 2];
                h8 s1 = H[(size_t)node * 2 + 1];
#pragma unroll
                for (int j = 0; j < 8; j++) { acc[j] = (float)s0[j]; acc[8 + j] = (float)s1[j]; }
            } else {
#pragma unroll
                for (int j = 0; j < 16; j++) acc[j] = 0.f;
            }
            int b0i = rs[node], e2 = re[node];
            int i = b0i + qt;
            for (; i + 12 < e2; i += 16) {
                int s0 = col2[i], s1 = col2[i + 4], s2 = col2[i + 8], s3 = col2[i + 12];
                h8 y0 = H[(size_t)s0 * 2], z0 = H[(size_t)s0 * 2 + 1];
                h8 y1 = H[(size_t)s1 * 2], z1 = H[(size_t)s1 * 2 + 1];
                h8 y2 = H[(size_t)s2 * 2], z2 = H[(size_t)s2 * 2 + 1];
                h8 y3 = H[(size_t)s3 * 2], z3 = H[(size_t)s3 * 2 + 1];
#pragma unroll
                for (int j = 0; j < 8; j++) {
                    acc[j]     += (float)y0[j] + (float)y1[j] + (float)y2[j] + (float)y3[j];
                    acc[8 + j] += (float)z0[j] + (float)z1[j] + (float)z2[j] + (float)z3[j];
                }
            }
            for (; i < e2; i += 4) {
                int s = col2[i];
                h8 y = H[(size_t)s * 2], z = H[(size_t)s * 2 + 1];
#pragma unroll
                for (int j = 0; j < 8; j++) { acc[j] += (float)y[j]; acc[8 + j] += (float)z[j]; }
            }
#pragma unroll
            for (int j = 0; j < 16; j++) {
                acc[j] += __shfl_xor(acc[j], 1);
                acc[j] += __shfl_xor(acc[j], 2);
            }
            float d = dis[node];
            float p0 = 0.f, p1 = 0.f;
#pragma unroll
            for (int k = 0; k < 16; k++) {
                float v = acc[k] * d + su.p.sb[k];
                v = v > 0.f ? v : 0.f;
                p0 += v * su.p.sW[k * 2 + 0];
                p1 += v * su.p.sW[k * 2 + 1];
            }
            if (qt == 0) {
                h2v o;
                o[0] = (_Float16)(p0 * d);
                o[1] = (_Float16)(p1 * d);
                ((h2v*)hs2)[node] = o;
            }
        }
    }
    gsync(grid);

    // ---------- P6: agg3 + bias + log_softmax (4 lanes/node) ----------
    {
        const h2v* H = (const h2v*)hs2;
        float bz0 = bias3[0], bz1 = bias3[1];
        long long stride = (long long)gridDim.x * 512;
        for (long long t = (long long)blockIdx.x * 512 + tid; (t >> 2) < (long long)n; t += stride) {
            int node = (int)(t >> 2), qt = (int)(t & 3);
            float a0 = 0.f, a1 = 0.f;
            if (qt == 0) {
                h2v self = H[node];
                a0 = (float)self[0]; a1 = (float)self[1];
            }
            int b0i = rs[node], e2 = re[node];
            int i = b0i + qt;
            for (; i + 12 < e2; i += 16) {
                h2v v0 = H[col2[i]];
                h2v v1 = H[col2[i + 4]];
                h2v v2 = H[col2[i + 8]];
                h2v v3 = H[col2[i + 12]];
                a0 += (float)v0[0] + (float)v1[0] + (float)v2[0] + (float)v3[0];
                a1 += (float)v0[1] + (float)v1[1] + (float)v2[1] + (float)v3[1];
            }
            for (; i < e2; i += 4) {
                h2v v = H[col2[i]];
                a0 += (float)v[0];
                a1 += (float)v[1];
            }
            a0 += __shfl_xor(a0, 1); a0 += __shfl_xor(a0, 2);
            a1 += __shfl_xor(a1, 1); a1 += __shfl_xor(a1, 2);
            if (qt == 0) {
                float d = dis[node];
                float z0 = a0 * d + bz0;
                float z1 = a1 * d + bz1;
                float m = fmaxf(z0, z1);
                float l = m + logf(expf(z0 - m) + expf(z1 - m));
                float2 o = {z0 - l, z1 - l};
                ((float2*)out)[node] = o;
            }
        }
    }
}

// ================= launch =================

extern "C" void kernel_launch(void* const* d_in, const int* in_sizes, int n_in,
                              void* d_out, int out_size, void* d_ws, size_t ws_size,
                              hipStream_t stream) {
    const float* x  = (const float*)d_in[0];
    const int*   ei = (const int*)d_in[1];
    const float* W1 = (const float*)d_in[2];
    const float* b1 = (const float*)d_in[3];
    const float* W2 = (const float*)d_in[4];
    const float* b2 = (const float*)d_in[5];
    const float* W3 = (const float*)d_in[6];
    const float* b3 = (const float*)d_in[7];
    float* out = (float*)d_out;

    int N = in_sizes[0] / 128;
    int E = in_sizes[1] / 2;
    const int* src = ei;
    const int* dst = ei + E;

    int NBUCK = (N + BKN - 1) >> BSH;            // 391 for N=100000 (<= 512)
    int ES = (E + NSB - 1) / NSB;                // 6250 (<= ESMAX)

    char* ws = (char*)d_ws;
    size_t off = 0;
    auto alloc = [&](size_t bytes) {
        void* p = ws + off;
        off += (bytes + 255) & ~(size_t)255;
        return p;
    };
    int*       gcur = (int*)alloc((size_t)NBUCK * sizeof(int));
    unsigned*  col  = (unsigned*)alloc((size_t)NBUCK * SLOT * sizeof(unsigned));
    int*       col2 = (int*)alloc((size_t)NBUCK * SLOT * sizeof(int));
    int*       rs   = (int*)alloc((size_t)N * sizeof(int));
    int*       re   = (int*)alloc((size_t)N * sizeof(int));
    float*     dis  = (float*)alloc((size_t)N * sizeof(float));
    _Float16*  hsA  = (_Float16*)alloc((size_t)N * 16 * sizeof(_Float16));
    _Float16*  hsB  = (_Float16*)alloc((size_t)N * 16 * sizeof(_Float16));
    _Float16*  hs2  = (_Float16*)alloc((size_t)N * 2 * sizeof(_Float16));

    // Co-resident grid size (cached): blocks/CU from occupancy API x CU count.
    static int gridBlocks = 0;
    if (gridBlocks == 0) {
        int mb = 0;
        if (hipOccupancyMaxActiveBlocksPerMultiprocessor(&mb, k_mega, 512, 0) != hipSuccess || mb < 1)
            mb = 2;   // known-safe: 43KB LDS, 128 VGPR -> 2 blocks/CU
        int ncu = 256;
        int dev = 0;
        hipGetDevice(&dev);
        hipDeviceGetAttribute(&ncu, hipDeviceAttributeMultiprocessorCount, dev);
        long long g = (long long)mb * ncu;
        if (g > 1024) g = 1024;
        gridBlocks = (int)g;
    }

    // zero bucket cursors (replaces in-kernel P0 + one grid sync)
    hipMemsetAsync(gcur, 0, (size_t)NBUCK * sizeof(int), stream);

    void* args[] = { &x, &src, &dst, &W1, &b1, &W2, &b2, &W3, &b3,
                     &gcur, &col, &col2, &rs, &re, &dis, &hsA, &hsB, &hs2,
                     &out, &N, &E, &NBUCK, &ES };
    hipLaunchCooperativeKernel((void*)k_mega, dim3(gridBlocks), dim3(512),
                               args, 0, stream);
}

// Round 5
// 822.704 us; speedup vs baseline: 1.0919x; 1.0007x over previous
//
#include <hip/hip_runtime.h>
#include <hip/hip_cooperative_groups.h>
#include <math.h>

#define BSH   8     // 256 nodes per bucket
#define BKN   256   // nodes per bucket
#define ESMAX 3200  // max edges per chunk (>=1024 chunks over 3.2M edges)
#define SLOT  10240 // col/col2 region size per bucket (avg fill 8192, +23 sigma)

typedef _Float16 h8  __attribute__((ext_vector_type(8)));
typedef _Float16 h4  __attribute__((ext_vector_type(4)));
typedef _Float16 h2v __attribute__((ext_vector_type(2)));

// Shared-memory overlay. Max member = bucket phase: 24.2 KB.
// (round-4 lesson: LDS no longer the residency limiter; wave slots are.)
union SU {
    struct {
        unsigned sorted[ESMAX];
        int lc[512], lofE[512], lcur[512], soff[512];
        int wsum[8];
        unsigned char sbuck[ESMAX];
    } b;                                        // 24224 B
    struct { int cnt[BKN], cur[BKN], wsum[4]; } s;
    struct { float sW[2048]; } l;               // linear1 weights
    struct { float sW[256]; float sb[16]; } p;  // pull epilogues
};

// 64-lane inclusive scan (no barriers)
__device__ inline int wave_scan_incl(int v) {
    int lane = threadIdx.x & 63;
#pragma unroll
    for (int d = 1; d < 64; d <<= 1) {
        int t = __shfl_up(v, d, 64);
        if (lane >= d) v += t;
    }
    return v;
}

__device__ inline void gsync(cooperative_groups::grid_group& g) {
    __threadfence();
    g.sync();
    __threadfence();
}

// ================= one cooperative kernel, 6 phases =================
// Phase code fits a 64-VGPR budget without spilling (max live set ~50 regs).

__global__ __attribute__((amdgpu_flat_work_group_size(512, 512)))
void k_mega(
        const float* __restrict__ x, const int* __restrict__ srcv, const int* __restrict__ dstv,
        const float* __restrict__ W1, const float* __restrict__ bias1,
        const float* __restrict__ W2, const float* __restrict__ bias2,
        const float* __restrict__ W3, const float* __restrict__ bias3,
        int* __restrict__ gcur, unsigned* __restrict__ col, int* __restrict__ col2,
        int* __restrict__ rs, int* __restrict__ re, float* __restrict__ dis,
        _Float16* __restrict__ hsA, _Float16* __restrict__ hsB, _Float16* __restrict__ hs2,
        float* __restrict__ out, int n, int e, int nbuck, int es)
{
    cooperative_groups::grid_group grid = cooperative_groups::this_grid();
    __shared__ SU su;
    int tid = threadIdx.x;

    // ---------- P1: bucket pass (LDS counting sort + atomic region alloc) ----------
    for (long long blk = blockIdx.x; blk * es < e; blk += gridDim.x) {
        su.b.lc[tid] = 0;
        __syncthreads();
        int lo = (int)(blk * es);
        int hi = min(lo + es, e);
        for (int i = lo + tid; i < hi; i += 512)
            atomicAdd(&su.b.lc[dstv[i] >> BSH], 1);
        __syncthreads();
        int c = su.b.lc[tid];
        int inc = wave_scan_incl(c);
        int wid = tid >> 6;
        if ((tid & 63) == 63) su.b.wsum[wid] = inc;
        __syncthreads();
        int wofs = 0;
#pragma unroll
        for (int w = 0; w < 8; w++) wofs += (w < wid) ? su.b.wsum[w] : 0;
        int excl = inc - c + wofs;
        su.b.lofE[tid] = excl;
        su.b.lcur[tid] = excl;
        if (tid < nbuck && c > 0)
            su.b.soff[tid] = tid * SLOT + atomicAdd(&gcur[tid], c);
        __syncthreads();
        for (int i = lo + tid; i < hi; i += 512) {
            int d = dstv[i];
            int bb = d >> BSH;
            int p = atomicAdd(&su.b.lcur[bb], 1);
            su.b.sorted[p] = ((unsigned)srcv[i] << BSH) | (unsigned)(d & (BKN - 1));
            su.b.sbuck[p] = (unsigned char)(bb & 255);
        }
        __syncthreads();
        int cnt_ = hi - lo;
        int split = (nbuck > 256) ? su.b.lofE[256] : 0x7fffffff;
        for (int i = tid; i < cnt_; i += 512) {
            int bb = su.b.sbuck[i] | ((i >= split) ? 256 : 0);
            col[su.b.soff[bb] + (i - su.b.lofE[bb])] = su.b.sorted[i];
        }
        __syncthreads();
    }
    gsync(grid);

    // ---------- P2: per-bucket counting sort -> CSR + dis (direct global scatter) ----------
    for (int bk = blockIdx.x; bk < nbuck; bk += gridDim.x) {
        int lo = bk * SLOT;
        int tot = gcur[bk];
        int hi = lo + tot;
        if (tid < BKN) su.s.cnt[tid] = 0;
        __syncthreads();
        for (int i = lo + tid; i < hi; i += 512)
            atomicAdd(&su.s.cnt[col[i] & (BKN - 1u)], 1);
        __syncthreads();
        int c = (tid < BKN) ? su.s.cnt[tid] : 0;
        int inc = wave_scan_incl(c);
        int wid = tid >> 6;
        if (tid < BKN && (tid & 63) == 63) su.s.wsum[wid] = inc;
        __syncthreads();
        if (tid < BKN) {
            int wofs = 0;
#pragma unroll
            for (int w = 0; w < 4; w++) wofs += (w < wid) ? su.s.wsum[w] : 0;
            int excl = inc - c + wofs;
            su.s.cur[tid] = lo + excl;
            int node = (bk << BSH) + tid;
            if (node < n) {
                rs[node] = lo + excl;
                re[node] = lo + excl + c;
                dis[node] = rsqrtf((float)(c + 1));
            }
        }
        __syncthreads();
        for (int i = lo + tid; i < hi; i += 512) {
            unsigned v = col[i];
            int pos = atomicAdd(&su.s.cur[v & (BKN - 1u)], 1);
            col2[pos] = (int)(v >> BSH);
        }
        __syncthreads();
    }
    gsync(grid);

    // ---------- P3: layer-1 linear  hsA = (x @ W1) * dis ----------
    // 64 threads/node: kg in [0,16) covers 8 k's (wr[8][4] = 32 regs),
    // cgi in [0,4) covers 4 cols. Reduce over kg lanes via shfl_xor 4..32.
    {
        for (int i = tid; i < 2048; i += 512) su.l.sW[i] = W1[i];
        __syncthreads();
        int cgi = tid & 3;
        int kg  = (tid >> 2) & 15;
        int wv  = tid >> 6;
        float wr[8][4];
#pragma unroll
        for (int j = 0; j < 8; j++)
#pragma unroll
            for (int cc = 0; cc < 4; cc++)
                wr[j][cc] = su.l.sW[(kg * 8 + j) * 16 + cgi * 4 + cc];
        for (int base = blockIdx.x * 8; base < n; base += gridDim.x * 8) {
            int node = base + wv;
            float a0 = 0.f, a1 = 0.f, a2 = 0.f, a3 = 0.f;
            if (node < n) {
                const float4* xr = (const float4*)(x + (size_t)node * 128 + kg * 8);
                float4 xv0 = xr[0], xv1 = xr[1];
                float xs[8] = {xv0.x, xv0.y, xv0.z, xv0.w, xv1.x, xv1.y, xv1.z, xv1.w};
#pragma unroll
                for (int j = 0; j < 8; j++) {
                    a0 += xs[j] * wr[j][0];
                    a1 += xs[j] * wr[j][1];
                    a2 += xs[j] * wr[j][2];
                    a3 += xs[j] * wr[j][3];
                }
            }
#pragma unroll
            for (int m = 4; m <= 32; m <<= 1) {
                a0 += __shfl_xor(a0, m);
                a1 += __shfl_xor(a1, m);
                a2 += __shfl_xor(a2, m);
                a3 += __shfl_xor(a3, m);
            }
            if (kg == 0 && node < n) {
                float d = dis[node];
                h4 o;
                o[0] = (_Float16)(a0 * d);
                o[1] = (_Float16)(a1 * d);
                o[2] = (_Float16)(a2 * d);
                o[3] = (_Float16)(a3 * d);
                *((h4*)(hsA + (size_t)node * 16 + cgi * 4)) = o;
            }
        }
    }
    gsync(grid);

    // ---------- P4: agg1 + 16x16 linear (4 lanes/node, 2-edge unroll) ----------
    {
        if (tid < 256) su.p.sW[tid] = W2[tid];
        if (tid < 16)  su.p.sb[tid] = bias1[tid];
        __syncthreads();
        const h8* H = (const h8*)hsA;
        long long stride = (long long)gridDim.x * 512;
        for (long long t = (long long)blockIdx.x * 512 + tid; (t >> 2) < (long long)n; t += stride) {
            int node = (int)(t >> 2), qt = (int)(t & 3);
            float acc[16];
            if (qt == 0) {
                h8 s0 = H[(size_t)node * 2];
                h8 s1 = H[(size_t)node * 2 + 1];
#pragma unroll
                for (int j = 0; j < 8; j++) { acc[j] = (float)s0[j]; acc[8 + j] = (float)s1[j]; }
            } else {
#pragma unroll
                for (int j = 0; j < 16; j++) acc[j] = 0.f;
            }
            int b0i = rs[node], e2 = re[node];
            int i = b0i + qt;
            for (; i + 4 < e2; i += 8) {
                int s0 = col2[i], s1 = col2[i + 4];
                h8 y0 = H[(size_t)s0 * 2], z0 = H[(size_t)s0 * 2 + 1];
                h8 y1 = H[(size_t)s1 * 2], z1 = H[(size_t)s1 * 2 + 1];
#pragma unroll
                for (int j = 0; j < 8; j++) {
                    acc[j]     += (float)y0[j] + (float)y1[j];
                    acc[8 + j] += (float)z0[j] + (float)z1[j];
                }
            }
            for (; i < e2; i += 4) {
                int s = col2[i];
                h8 y = H[(size_t)s * 2], z = H[(size_t)s * 2 + 1];
#pragma unroll
                for (int j = 0; j < 8; j++) { acc[j] += (float)y[j]; acc[8 + j] += (float)z[j]; }
            }
#pragma unroll
            for (int j = 0; j < 16; j++) {
                acc[j] += __shfl_xor(acc[j], 1);
                acc[j] += __shfl_xor(acc[j], 2);
            }
            float d = dis[node];
            float va[16];
#pragma unroll
            for (int k = 0; k < 16; k++) {
                float v = acc[k] * d + su.p.sb[k];
                va[k] = v > 0.f ? v : 0.f;
            }
            h4 o;
#pragma unroll
            for (int cc = 0; cc < 4; cc++) {
                int cidx = (qt << 2) + cc;
                float s = 0.f;
#pragma unroll
                for (int k = 0; k < 16; k++) s += va[k] * su.p.sW[k * 16 + cidx];
                o[cc] = (_Float16)(s * d);
            }
            *((h4*)(hsB + (size_t)node * 16 + (qt << 2))) = o;
        }
    }
    gsync(grid);

    // ---------- P5: agg2 + 16x2 linear (4 lanes/node, 2-edge unroll) ----------
    {
        if (tid < 32) su.p.sW[tid] = W3[tid];
        if (tid < 16) su.p.sb[tid] = bias2[tid];
        __syncthreads();
        const h8* H = (const h8*)hsB;
        long long stride = (long long)gridDim.x * 512;
        for (long long t = (long long)blockIdx.x * 512 + tid; (t >> 2) < (long long)n; t += stride) {
            int node = (int)(t >> 2), qt = (int)(t & 3);
            float acc[16];
            if (qt == 0) {
                h8 s0 = H[(size_t)node * 2];
                h8 s1 = H[(size_t)node * 2 + 1];
#pragma unroll
                for (int j = 0; j < 8; j++) { acc[j] = (float)s0[j]; acc[8 + j] = (float)s1[j]; }
            } else {
#pragma unroll
                for (int j = 0; j < 16; j++) acc[j] = 0.f;
            }
            int b0i = rs[node], e2 = re[node];
            int i = b0i + qt;
            for (; i + 4 < e2; i += 8) {
                int s0 = col2[i], s1 = col2[i + 4];
                h8 y0 = H[(size_t)s0 * 2], z0 = H[(size_t)s0 * 2 + 1];
                h8 y1 = H[(size_t)s1 * 2], z1 = H[(size_t)s1 * 2 + 1];
#pragma unroll
                for (int j = 0; j < 8; j++) {
                    acc[j]     += (float)y0[j] + (float)y1[j];
                    acc[8 + j] += (float)z0[j] + (float)z1[j];
                }
            }
            for (; i < e2; i += 4) {
                int s = col2[i];
                h8 y = H[(size_t)s * 2], z = H[(size_t)s * 2 + 1];
#pragma unroll
                for (int j = 0; j < 8; j++) { acc[j] += (float)y[j]; acc[8 + j] += (float)z[j]; }
            }
#pragma unroll
            for (int j = 0; j < 16; j++) {
                acc[j] += __shfl_xor(acc[j], 1);
                acc[j] += __shfl_xor(acc[j], 2);
            }
            float d = dis[node];
            float p0 = 0.f, p1 = 0.f;
#pragma unroll
            for (int k = 0; k < 16; k++) {
                float v = acc[k] * d + su.p.sb[k];
                v = v > 0.f ? v : 0.f;
                p0 += v * su.p.sW[k * 2 + 0];
                p1 += v * su.p.sW[k * 2 + 1];
            }
            if (qt == 0) {
                h2v o;
                o[0] = (_Float16)(p0 * d);
                o[1] = (_Float16)(p1 * d);
                ((h2v*)hs2)[node] = o;
            }
        }
    }
    gsync(grid);

    // ---------- P6: agg3 + bias + log_softmax (4 lanes/node) ----------
    {
        const h2v* H = (const h2v*)hs2;
        float bz0 = bias3[0], bz1 = bias3[1];
        long long stride = (long long)gridDim.x * 512;
        for (long long t = (long long)blockIdx.x * 512 + tid; (t >> 2) < (long long)n; t += stride) {
            int node = (int)(t >> 2), qt = (int)(t & 3);
            float a0 = 0.f, a1 = 0.f;
            if (qt == 0) {
                h2v self = H[node];
                a0 = (float)self[0]; a1 = (float)self[1];
            }
            int b0i = rs[node], e2 = re[node];
            int i = b0i + qt;
            for (; i + 12 < e2; i += 16) {
                h2v v0 = H[col2[i]];
                h2v v1 = H[col2[i + 4]];
                h2v v2 = H[col2[i + 8]];
                h2v v3 = H[col2[i + 12]];
                a0 += (float)v0[0] + (float)v1[0] + (float)v2[0] + (float)v3[0];
                a1 += (float)v0[1] + (float)v1[1] + (float)v2[1] + (float)v3[1];
            }
            for (; i < e2; i += 4) {
                h2v v = H[col2[i]];
                a0 += (float)v[0];
                a1 += (float)v[1];
            }
            a0 += __shfl_xor(a0, 1); a0 += __shfl_xor(a0, 2);
            a1 += __shfl_xor(a1, 1); a1 += __shfl_xor(a1, 2);
            if (qt == 0) {
                float d = dis[node];
                float z0 = a0 * d + bz0;
                float z1 = a1 * d + bz1;
                float m = fmaxf(z0, z1);
                float l = m + logf(expf(z0 - m) + expf(z1 - m));
                float2 o = {z0 - l, z1 - l};
                ((float2*)out)[node] = o;
            }
        }
    }
}

// ================= launch =================

extern "C" void kernel_launch(void* const* d_in, const int* in_sizes, int n_in,
                              void* d_out, int out_size, void* d_ws, size_t ws_size,
                              hipStream_t stream) {
    const float* x  = (const float*)d_in[0];
    const int*   ei = (const int*)d_in[1];
    const float* W1 = (const float*)d_in[2];
    const float* b1 = (const float*)d_in[3];
    const float* W2 = (const float*)d_in[4];
    const float* b2 = (const float*)d_in[5];
    const float* W3 = (const float*)d_in[6];
    const float* b3 = (const float*)d_in[7];
    float* out = (float*)d_out;

    int N = in_sizes[0] / 128;
    int E = in_sizes[1] / 2;
    const int* src = ei;
    const int* dst = ei + E;

    int NBUCK = (N + BKN - 1) >> BSH;            // 391 for N=100000

    char* ws = (char*)d_ws;
    size_t off = 0;
    auto alloc = [&](size_t bytes) {
        void* p = ws + off;
        off += (bytes + 255) & ~(size_t)255;
        return p;
    };
    int*       gcur = (int*)alloc((size_t)NBUCK * sizeof(int));
    unsigned*  col  = (unsigned*)alloc((size_t)NBUCK * SLOT * sizeof(unsigned));
    int*       col2 = (int*)alloc((size_t)NBUCK * SLOT * sizeof(int));
    int*       rs   = (int*)alloc((size_t)N * sizeof(int));
    int*       re   = (int*)alloc((size_t)N * sizeof(int));
    float*     dis  = (float*)alloc((size_t)N * sizeof(float));
    _Float16*  hsA  = (_Float16*)alloc((size_t)N * 16 * sizeof(_Float16));
    _Float16*  hsB  = (_Float16*)alloc((size_t)N * 16 * sizeof(_Float16));
    _Float16*  hs2  = (_Float16*)alloc((size_t)N * 2 * sizeof(_Float16));

    // Grid: API-driven but HARD-CLAMPED to <=3 blocks/CU (round-3-proven
    // residency class; round 4's 4 blocks/CU = 32 waves/CU failed to launch).
    static int gridBlocks = 0;
    if (gridBlocks == 0) {
        int mb = 0;
        if (hipOccupancyMaxActiveBlocksPerMultiprocessor(&mb, k_mega, 512, 0) != hipSuccess || mb < 1)
            mb = 2;
        if (mb > 3) mb = 3;
        int ncu = 256;
        int dev = 0;
        hipGetDevice(&dev);
        hipDeviceGetAttribute(&ncu, hipDeviceAttributeMultiprocessorCount, dev);
        long long g = (long long)mb * ncu;
        if (g > 768) g = 768;
        gridBlocks = (int)g;
    }

    // edge chunking: at least 1024 chunks so ES stays within the 24KB LDS budget
    int nch = gridBlocks > 1024 ? gridBlocks : 1024;
    int ES = (E + nch - 1) / nch;
    if (ES > ESMAX - 16) ES = ESMAX - 16;

    // zero bucket cursors
    hipMemsetAsync(gcur, 0, (size_t)NBUCK * sizeof(int), stream);

    void* args[] = { &x, &src, &dst, &W1, &b1, &W2, &b2, &W3, &b3,
                     &gcur, &col, &col2, &rs, &re, &dis, &hsA, &hsB, &hs2,
                     &out, &N, &E, &NBUCK, &ES };

    // Launch with fallback: never silently drop the dispatch (round-4 lesson).
    int gb = gridBlocks;
    hipError_t err = hipLaunchCooperativeKernel((void*)k_mega, dim3(gb), dim3(512),
                                                args, 0, stream);
    while (err != hipSuccess && gb > 128) {
        gb >>= 1;
        err = hipLaunchCooperativeKernel((void*)k_mega, dim3(gb), dim3(512),
                                         args, 0, stream);
    }
    if (err == hipSuccess && gb != gridBlocks) gridBlocks = gb;  // remember working size
}

// Round 6
// 261.062 us; speedup vs baseline: 3.4410x; 3.1514x over previous
//
#include <hip/hip_runtime.h>
#include <math.h>

#define NSB   512   // edge-chunk blocks for bucket pass
#define BSH   8     // 256 nodes per bucket
#define BKN   256   // nodes per bucket
#define ESMAX 6272  // max edges per chunk (ceil(3.2M/512)=6250)
#define SLOT  10240 // col/col2 region size per bucket (avg fill 8192, +23 sigma)

typedef _Float16 h8  __attribute__((ext_vector_type(8)));
typedef _Float16 h4  __attribute__((ext_vector_type(4)));
typedef _Float16 h2v __attribute__((ext_vector_type(2)));

// 64-lane inclusive scan (no barriers)
__device__ inline int wave_scan_incl(int v) {
    int lane = threadIdx.x & 63;
#pragma unroll
    for (int d = 1; d < 64; d <<= 1) {
        int t = __shfl_up(v, d, 64);
        if (lane >= d) v += t;
    }
    return v;
}

// ================= fused bucket + linear1(unscaled): one dispatch, blockIdx split =================
// Blocks [0, NSB): edge bucket pass (LDS counting sort + atomic region alloc).
// Blocks [NSB, NSB+nlin): hsRaw = x @ W1 (fp16, unscaled; dis applied later in k_sort2).
// Rationale: x@W1 is independent of the CSR build -> co-schedule in one dispatch
// (bucket = LDS/atomic-bound, linear = BW/FLOP-bound), saving a dispatch gap.

union BU {
    struct {
        unsigned sorted[ESMAX];
        int lc[512], lofE[512], lcur[512], soff[512];
        int wsum[8];
        unsigned char sbuck[ESMAX];
    } b;                              // 39584 B
    struct { float sW[2048]; } l;     // 8 KB
};

__global__ __launch_bounds__(512) void k_build(
        const int* __restrict__ srcv, const int* __restrict__ dstv,
        const float* __restrict__ x, const float* __restrict__ W1,
        int* __restrict__ gcur, unsigned* __restrict__ col,
        _Float16* __restrict__ hsRaw,
        int e, int nbuck, int es, int n, int nlin) {
    __shared__ BU su;
    int tid = threadIdx.x;

    if (blockIdx.x < NSB) {
        // ---- bucket pass (verbatim r1 logic) ----
        su.b.lc[tid] = 0;
        __syncthreads();
        int lo = blockIdx.x * es;
        int hi = min(lo + es, e);
        for (int i = lo + tid; i < hi; i += 512)
            atomicAdd(&su.b.lc[dstv[i] >> BSH], 1);
        __syncthreads();
        int c = su.b.lc[tid];
        int inc = wave_scan_incl(c);
        int wid = tid >> 6;
        if ((tid & 63) == 63) su.b.wsum[wid] = inc;
        __syncthreads();
        int wofs = 0;
#pragma unroll
        for (int w = 0; w < 8; w++) wofs += (w < wid) ? su.b.wsum[w] : 0;
        int excl = inc - c + wofs;
        su.b.lofE[tid] = excl;
        su.b.lcur[tid] = excl;
        if (tid < nbuck && c > 0)
            su.b.soff[tid] = tid * SLOT + atomicAdd(&gcur[tid], c);
        __syncthreads();
        for (int i = lo + tid; i < hi; i += 512) {
            int d = dstv[i];
            int bb = d >> BSH;
            int p = atomicAdd(&su.b.lcur[bb], 1);
            su.b.sorted[p] = ((unsigned)srcv[i] << BSH) | (unsigned)(d & (BKN - 1));
            su.b.sbuck[p] = (unsigned char)(bb & 255);
        }
        __syncthreads();
        int cnt_ = hi - lo;
        int split = (nbuck > 256) ? su.b.lofE[256] : 0x7fffffff;
        for (int i = tid; i < cnt_; i += 512) {
            int bb = su.b.sbuck[i] | ((i >= split) ? 256 : 0);
            col[su.b.soff[bb] + (i - su.b.lofE[bb])] = su.b.sorted[i];
        }
    } else {
        // ---- linear1 raw: 64 threads/node, register-lean (wr[8][4] = 32 regs) ----
        for (int i = tid; i < 2048; i += 512) su.l.sW[i] = W1[i];
        __syncthreads();
        int cgi = tid & 3;
        int kg  = (tid >> 2) & 15;
        int wv  = tid >> 6;
        float wr[8][4];
#pragma unroll
        for (int j = 0; j < 8; j++)
#pragma unroll
            for (int cc = 0; cc < 4; cc++)
                wr[j][cc] = su.l.sW[(kg * 8 + j) * 16 + cgi * 4 + cc];
        int lb = blockIdx.x - NSB;
        for (int base = lb * 8; base < n; base += nlin * 8) {
            int node = base + wv;
            float a0 = 0.f, a1 = 0.f, a2 = 0.f, a3 = 0.f;
            if (node < n) {
                const float4* xr = (const float4*)(x + (size_t)node * 128 + kg * 8);
                float4 xv0 = xr[0], xv1 = xr[1];
                float xs[8] = {xv0.x, xv0.y, xv0.z, xv0.w, xv1.x, xv1.y, xv1.z, xv1.w};
#pragma unroll
                for (int j = 0; j < 8; j++) {
                    a0 += xs[j] * wr[j][0];
                    a1 += xs[j] * wr[j][1];
                    a2 += xs[j] * wr[j][2];
                    a3 += xs[j] * wr[j][3];
                }
            }
#pragma unroll
            for (int m = 4; m <= 32; m <<= 1) {
                a0 += __shfl_xor(a0, m);
                a1 += __shfl_xor(a1, m);
                a2 += __shfl_xor(a2, m);
                a3 += __shfl_xor(a3, m);
            }
            if (kg == 0 && node < n) {
                h4 o;
                o[0] = (_Float16)a0;
                o[1] = (_Float16)a1;
                o[2] = (_Float16)a2;
                o[3] = (_Float16)a3;
                *((h4*)(hsRaw + (size_t)node * 16 + cgi * 4)) = o;
            }
        }
    }
}

// ================= per-bucket counting sort -> CSR + dis, then scale hsRaw -> hsA =================

__global__ __launch_bounds__(512) void k_sort2(
        const unsigned* __restrict__ col, const int* __restrict__ gcur,
        int* __restrict__ col2, int* __restrict__ rs,
        int* __restrict__ re, float* __restrict__ dis,
        const _Float16* __restrict__ hsRaw, _Float16* __restrict__ hsA, int n) {
    __shared__ int cnt[BKN];
    __shared__ int cur[BKN];
    __shared__ int wsum[4];
    __shared__ float sdis[BKN];
    int tid = threadIdx.x;
    int bk = blockIdx.x;
    int lo = bk * SLOT;
    int hi = lo + gcur[bk];
    if (tid < BKN) cnt[tid] = 0;
    __syncthreads();
    for (int i = lo + tid; i < hi; i += 512)
        atomicAdd(&cnt[col[i] & (BKN - 1u)], 1);
    __syncthreads();
    int c = (tid < BKN) ? cnt[tid] : 0;
    int inc = wave_scan_incl(c);
    int wid = tid >> 6;
    if (tid < BKN && (tid & 63) == 63) wsum[wid] = inc;
    __syncthreads();
    if (tid < BKN) {
        int wofs = 0;
#pragma unroll
        for (int w = 0; w < 4; w++) wofs += (w < wid) ? wsum[w] : 0;
        int excl = inc - c + wofs;
        cur[tid] = lo + excl;
        float d = rsqrtf((float)(c + 1));
        sdis[tid] = d;
        int node = (bk << BSH) + tid;
        if (node < n) {
            rs[node] = lo + excl;
            re[node] = lo + excl + c;
            dis[node] = d;
        }
    }
    __syncthreads();
    // scatter col2 (strided global; r0 A/B showed LDS staging is perf-neutral)
    for (int i = lo + tid; i < hi; i += 512) {
        unsigned v = col[i];
        int pos = atomicAdd(&cur[v & (BKN - 1u)], 1);
        col2[pos] = (int)(v >> BSH);
    }
    // deferred dis scaling of this bucket's 256 hs rows (independent of scatter)
    {
        int node = (bk << BSH) + (tid >> 1);
        if (node < n) {
            float d = sdis[tid >> 1];
            h8 v = ((const h8*)hsRaw)[(size_t)node * 2 + (tid & 1)];
            h8 o;
#pragma unroll
            for (int j = 0; j < 8; j++) o[j] = (_Float16)((float)v[j] * d);
            ((h8*)hsA)[(size_t)node * 2 + (tid & 1)] = o;
        }
    }
}

// ================= fused pull + 16x16 linear (4 threads/node) — r1 verbatim =================

__global__ __launch_bounds__(256) void k_pullA(
        const _Float16* __restrict__ hs, const int* __restrict__ rs,
        const int* __restrict__ re, const int* __restrict__ col2,
        const float* __restrict__ dis, const float* __restrict__ bb,
        const float* __restrict__ W, _Float16* __restrict__ hsOut, int n) {
    __shared__ float sW[256];
    __shared__ float sb[16];
    if (threadIdx.x < 256) sW[threadIdx.x] = W[threadIdx.x];
    if (threadIdx.x < 16) sb[threadIdx.x] = bb[threadIdx.x];
    __syncthreads();
    long long t = (long long)blockIdx.x * blockDim.x + threadIdx.x;
    int node = (int)(t >> 2), qt = (int)(t & 3);
    if (node >= n) return;
    const h8* H = (const h8*)hs;
    float acc[16];
    if (qt == 0) {
        h8 s0 = H[(size_t)node * 2];
        h8 s1 = H[(size_t)node * 2 + 1];
#pragma unroll
        for (int j = 0; j < 8; j++) { acc[j] = (float)s0[j]; acc[8 + j] = (float)s1[j]; }
    } else {
#pragma unroll
        for (int j = 0; j < 16; j++) acc[j] = 0.f;
    }
    int b = rs[node], e2 = re[node];
    int i = b + qt;
    for (; i + 12 < e2; i += 16) {
        int s0 = col2[i], s1 = col2[i + 4], s2 = col2[i + 8], s3 = col2[i + 12];
        h8 a0 = H[(size_t)s0 * 2], b0 = H[(size_t)s0 * 2 + 1];
        h8 a1 = H[(size_t)s1 * 2], b1 = H[(size_t)s1 * 2 + 1];
        h8 a2 = H[(size_t)s2 * 2], b2 = H[(size_t)s2 * 2 + 1];
        h8 a3 = H[(size_t)s3 * 2], b3 = H[(size_t)s3 * 2 + 1];
#pragma unroll
        for (int j = 0; j < 8; j++) {
            acc[j]     += (float)a0[j] + (float)a1[j] + (float)a2[j] + (float)a3[j];
            acc[8 + j] += (float)b0[j] + (float)b1[j] + (float)b2[j] + (float)b3[j];
        }
    }
    for (; i < e2; i += 4) {
        int s = col2[i];
        h8 a = H[(size_t)s * 2], bq = H[(size_t)s * 2 + 1];
#pragma unroll
        for (int j = 0; j < 8; j++) { acc[j] += (float)a[j]; acc[8 + j] += (float)bq[j]; }
    }
#pragma unroll
    for (int j = 0; j < 16; j++) {
        acc[j] += __shfl_xor(acc[j], 1);
        acc[j] += __shfl_xor(acc[j], 2);
    }
    float d = dis[node];
    float va[16];
#pragma unroll
    for (int k = 0; k < 16; k++) {
        float v = acc[k] * d + sb[k];
        va[k] = v > 0.f ? v : 0.f;
    }
    h4 o;
#pragma unroll
    for (int cc = 0; cc < 4; cc++) {
        int cidx = (qt << 2) + cc;
        float s = 0.f;
#pragma unroll
        for (int k = 0; k < 16; k++) s += va[k] * sW[k * 16 + cidx];
        o[cc] = (_Float16)(s * d);
    }
    *((h4*)(hsOut + (size_t)node * 16 + (qt << 2))) = o;
}

// ================= fused pull + 16x2 linear (4 threads/node) — r1 verbatim =================

__global__ __launch_bounds__(256) void k_pullB(
        const _Float16* __restrict__ hs, const int* __restrict__ rs,
        const int* __restrict__ re, const int* __restrict__ col2,
        const float* __restrict__ dis, const float* __restrict__ bb,
        const float* __restrict__ W, _Float16* __restrict__ hs2, int n) {
    __shared__ float sW[32];
    __shared__ float sb[16];
    if (threadIdx.x < 32) sW[threadIdx.x] = W[threadIdx.x];
    if (threadIdx.x < 16) sb[threadIdx.x] = bb[threadIdx.x];
    __syncthreads();
    long long t = (long long)blockIdx.x * blockDim.x + threadIdx.x;
    int node = (int)(t >> 2), qt = (int)(t & 3);
    if (node >= n) return;
    const h8* H = (const h8*)hs;
    float acc[16];
    if (qt == 0) {
        h8 s0 = H[(size_t)node * 2];
        h8 s1 = H[(size_t)node * 2 + 1];
#pragma unroll
        for (int j = 0; j < 8; j++) { acc[j] = (float)s0[j]; acc[8 + j] = (float)s1[j]; }
    } else {
#pragma unroll
        for (int j = 0; j < 16; j++) acc[j] = 0.f;
    }
    int b = rs[node], e2 = re[node];
    int i = b + qt;
    for (; i + 12 < e2; i += 16) {
        int s0 = col2[i], s1 = col2[i + 4], s2 = col2[i + 8], s3 = col2[i + 12];
        h8 a0 = H[(size_t)s0 * 2], b0 = H[(size_t)s0 * 2 + 1];
        h8 a1 = H[(size_t)s1 * 2], b1 = H[(size_t)s1 * 2 + 1];
        h8 a2 = H[(size_t)s2 * 2], b2 = H[(size_t)s2 * 2 + 1];
        h8 a3 = H[(size_t)s3 * 2], b3 = H[(size_t)s3 * 2 + 1];
#pragma unroll
        for (int j = 0; j < 8; j++) {
            acc[j]     += (float)a0[j] + (float)a1[j] + (float)a2[j] + (float)a3[j];
            acc[8 + j] += (float)b0[j] + (float)b1[j] + (float)b2[j] + (float)b3[j];
        }
    }
    for (; i < e2; i += 4) {
        int s = col2[i];
        h8 a = H[(size_t)s * 2], bq = H[(size_t)s * 2 + 1];
#pragma unroll
        for (int j = 0; j < 8; j++) { acc[j] += (float)a[j]; acc[8 + j] += (float)bq[j]; }
    }
#pragma unroll
    for (int j = 0; j < 16; j++) {
        acc[j] += __shfl_xor(acc[j], 1);
        acc[j] += __shfl_xor(acc[j], 2);
    }
    float d = dis[node];
    float p0 = 0.f, p1 = 0.f;
#pragma unroll
    for (int k = 0; k < 16; k++) {
        float v = acc[k] * d + sb[k];
        v = v > 0.f ? v : 0.f;
        p0 += v * sW[k * 2 + 0];
        p1 += v * sW[k * 2 + 1];
    }
    if (qt == 0) {
        h2v o;
        o[0] = (_Float16)(p0 * d);
        o[1] = (_Float16)(p1 * d);
        ((h2v*)hs2)[node] = o;
    }
}

// ================= final pull + bias + log_softmax (4 threads/node) — r1 verbatim =================

__global__ __launch_bounds__(256) void k_pull2lsm(
        const _Float16* __restrict__ hs2, const int* __restrict__ rs,
        const int* __restrict__ re, const int* __restrict__ col2,
        const float* __restrict__ dis, const float* __restrict__ b3,
        float* __restrict__ out, int n) {
    long long t = (long long)blockIdx.x * blockDim.x + threadIdx.x;
    int node = (int)(t >> 2), qt = (int)(t & 3);
    if (node >= n) return;
    const h2v* H = (const h2v*)hs2;
    float a0 = 0.f, a1 = 0.f;
    if (qt == 0) {
        h2v self = H[node];
        a0 = (float)self[0]; a1 = (float)self[1];
    }
    int b = rs[node], e2 = re[node];
    int i = b + qt;
    for (; i + 12 < e2; i += 16) {
        h2v v0 = H[col2[i]];
        h2v v1 = H[col2[i + 4]];
        h2v v2 = H[col2[i + 8]];
        h2v v3 = H[col2[i + 12]];
        a0 += (float)v0[0] + (float)v1[0] + (float)v2[0] + (float)v3[0];
        a1 += (float)v0[1] + (float)v1[1] + (float)v2[1] + (float)v3[1];
    }
    for (; i < e2; i += 4) {
        h2v v = H[col2[i]];
        a0 += (float)v[0];
        a1 += (float)v[1];
    }
    a0 += __shfl_xor(a0, 1); a0 += __shfl_xor(a0, 2);
    a1 += __shfl_xor(a1, 1); a1 += __shfl_xor(a1, 2);
    if (qt == 0) {
        float d = dis[node];
        float z0 = a0 * d + b3[0];
        float z1 = a1 * d + b3[1];
        float m = fmaxf(z0, z1);
        float l = m + logf(expf(z0 - m) + expf(z1 - m));
        float2 o = {z0 - l, z1 - l};
        ((float2*)out)[node] = o;
    }
}

// ================= launch =================

extern "C" void kernel_launch(void* const* d_in, const int* in_sizes, int n_in,
                              void* d_out, int out_size, void* d_ws, size_t ws_size,
                              hipStream_t stream) {
    const float* x  = (const float*)d_in[0];
    const int*   ei = (const int*)d_in[1];
    const float* W1 = (const float*)d_in[2];
    const float* b1 = (const float*)d_in[3];
    const float* W2 = (const float*)d_in[4];
    const float* b2 = (const float*)d_in[5];
    const float* W3 = (const float*)d_in[6];
    const float* b3 = (const float*)d_in[7];
    float* out = (float*)d_out;

    const int N = in_sizes[0] / 128;
    const int E = in_sizes[1] / 2;
    const int* src = ei;
    const int* dst = ei + E;

    const int NBUCK = (N + BKN - 1) >> BSH;      // 391 for N=100000 (<= 512)
    const int ES = (E + NSB - 1) / NSB;          // 6250 (<= ESMAX)
    const int NLIN = (N + 127) / 128;            // 782 linear blocks (8 nodes/sweep each)

    char* ws = (char*)d_ws;
    size_t off = 0;
    auto alloc = [&](size_t bytes) {
        void* p = ws + off;
        off += (bytes + 255) & ~(size_t)255;
        return p;
    };
    int*       gcur  = (int*)alloc((size_t)NBUCK * sizeof(int));
    unsigned*  col   = (unsigned*)alloc((size_t)NBUCK * SLOT * sizeof(unsigned));
    int*       col2  = (int*)alloc((size_t)NBUCK * SLOT * sizeof(int));
    int*       rs    = (int*)alloc((size_t)N * sizeof(int));
    int*       re    = (int*)alloc((size_t)N * sizeof(int));
    float*     dis   = (float*)alloc((size_t)N * sizeof(float));
    _Float16*  hsRaw = (_Float16*)alloc((size_t)N * 16 * sizeof(_Float16));
    _Float16*  hsA   = (_Float16*)alloc((size_t)N * 16 * sizeof(_Float16));
    _Float16*  hsB   = (_Float16*)alloc((size_t)N * 16 * sizeof(_Float16));
    _Float16*  hs2   = (_Float16*)alloc((size_t)N * 2 * sizeof(_Float16));

    const int B = 256;
    auto g = [&](long long work) { return (int)((work + B - 1) / B); };

    // ---- dispatch 1: zero region cursors ----
    hipMemsetAsync(gcur, 0, (size_t)NBUCK * sizeof(int), stream);

    // ---- dispatch 2: bucket pass || linear1 raw (merged, blockIdx split) ----
    k_build<<<NSB + NLIN, 512, 0, stream>>>(src, dst, x, W1, gcur, col, hsRaw,
                                            E, NBUCK, ES, N, NLIN);

    // ---- dispatch 3: per-bucket sort -> CSR + dis + scale hsRaw -> hsA ----
    k_sort2<<<NBUCK, 512, 0, stream>>>(col, gcur, col2, rs, re, dis, hsRaw, hsA, N);

    // ---- dispatch 4: agg1 + layer2 linear ----
    k_pullA<<<g((long long)N * 4), B, 0, stream>>>(hsA, rs, re, col2, dis, b1, W2, hsB, N);

    // ---- dispatch 5: agg2 + layer3 linear ----
    k_pullB<<<g((long long)N * 4), B, 0, stream>>>(hsB, rs, re, col2, dis, b2, W3, hs2, N);

    // ---- dispatch 6: agg3 + bias + log_softmax ----
    k_pull2lsm<<<g((long long)N * 4), B, 0, stream>>>(hs2, rs, re, col2, dis, b3, out, N);
}